// Round 11
// baseline (149.605 us; speedup 1.0000x reference)
//
#include <hip/hip_runtime.h>
#include <hip/hip_bf16.h>

#define S_LEN 1536
#define BATCH 2
#define DMODEL 1024
#define NHEAD 16
#define DHEAD 64
#define FDIM 384          // 2*DHEAD*N_ROLL
#define CHUNK 64
#define NCHUNK 24         // S_LEN / CHUNK
#define ROWS (S_LEN*BATCH)
#define SCALE_F 0.125f
#define EPS_D 1e-5f
#define EPS_LN 1e-5f

typedef unsigned short u16;
typedef __attribute__((ext_vector_type(8))) __bf16 bf16x8;
typedef __attribute__((ext_vector_type(8))) unsigned short ushort8;
typedef __attribute__((ext_vector_type(4))) float f32x4;

static __device__ __forceinline__ float bf2f(u16 a) {
  return __uint_as_float(((unsigned)a) << 16);
}
static __device__ __forceinline__ u16 f2bf(float x) {
  unsigned u = __float_as_uint(x);
  unsigned r = (u + 0x7FFFu + ((u >> 16) & 1u)) >> 16;
  return (u16)r;
}
static __device__ __forceinline__ void gload_lds16(const void* g, void* l) {
  __builtin_amdgcn_global_load_lds(
      (const __attribute__((address_space(1))) void*)g,
      (__attribute__((address_space(3))) void*)l, 16, 0, 0);
}
#define MFMA(a, b, c) __builtin_amdgcn_mfma_f32_16x16x32_bf16(a, b, c, 0, 0, 0)

static __device__ __forceinline__ void unpk(unsigned u, float& lo, float& hi) {
  lo = __uint_as_float(u << 16);
  hi = __uint_as_float(u & 0xffff0000u);
}

// Build feature A-fragment octet f=[m..m+8) for one y-row (s fixed):
// feat[e] = y[m+e] * y[(m+e-SH)&127]. SH constant-folds (callers unroll).
static __device__ __forceinline__ bf16x8 feat_frag(
    const u16* __restrict__ yrow, int m, int SH) {
  union U { ushort8 v; unsigned u[4]; };
  U y1, y0;
  y1.v = *(const ushort8*)(yrow + m);
  y0.v = *(const ushort8*)(yrow + ((m - 8) & 127));
  unsigned seq2 = y0.u[2], seq3 = y0.u[3];
  unsigned seq4 = y1.u[0], seq5 = y1.u[1], seq6 = y1.u[2], seq7 = y1.u[3];
  unsigned y2u[4];
  if (SH == 2) {                     // byte offset 12: pure dword select
    y2u[0] = seq3; y2u[1] = seq4; y2u[2] = seq5; y2u[3] = seq6;
  } else if (SH == 1) {              // byte offset 14
    y2u[0] = (seq3 >> 16) | (seq4 << 16);
    y2u[1] = (seq4 >> 16) | (seq5 << 16);
    y2u[2] = (seq5 >> 16) | (seq6 << 16);
    y2u[3] = (seq6 >> 16) | (seq7 << 16);
  } else {                           // SH==3, byte offset 10
    y2u[0] = (seq2 >> 16) | (seq3 << 16);
    y2u[1] = (seq3 >> 16) | (seq4 << 16);
    y2u[2] = (seq4 >> 16) | (seq5 << 16);
    y2u[3] = (seq5 >> 16) | (seq6 << 16);
  }
  bf16x8 out;
#pragma unroll
  for (int i = 0; i < 4; ++i) {
    float a0, a1, b0, b1;
    unpk(y1.u[i], a0, a1);
    unpk(y2u[i], b0, b1);
    out[2 * i] = (__bf16)(a0 * b0);
    out[2 * i + 1] = (__bf16)(a1 * b1);
  }
  return out;
}

// Fragment-tile layout: buffer [R][C] stored as [R/16][C/32][64][8] u16,
// lane l = kg*16+fr holds (row rT*16+fr, cols cB*32+kg*8 .. +8).

// One fused f32->bf16 convert for h, Wq, Wkv, Wo (quad-granular regions).
__global__ __launch_bounds__(256) void cvt_all(
    const float* __restrict__ h, const float* __restrict__ Wq,
    const float* __restrict__ Wkv, const float* __restrict__ Wo,
    u16* __restrict__ h_bf, u16* __restrict__ Wqkv_bf, u16* __restrict__ Wo_bf) {
  int i = blockIdx.x * 256 + threadIdx.x;   // quad index, 1835008 total
  const float* src; u16* dst; int j;
  if (i < 786432) { src = h; dst = h_bf; j = i; }
  else if (i < 1048576) { src = Wq; dst = Wqkv_bf; j = i - 786432; }
  else if (i < 1572864) { src = Wkv; dst = Wqkv_bf + 1048576; j = i - 1048576; }
  else { src = Wo; dst = Wo_bf; j = i - 1572864; }
  float4 v = ((const float4*)src)[j];
  ushort4 o = {f2bf(v.x), f2bf(v.y), f2bf(v.z), f2bf(v.w)};
  ((ushort4*)dst)[j] = o;
}

// QKV projection: C[M][N] = A[M][K]*B[N][K]^T, bf16 in, bf16 out.
// 128x128 tile, BK=32, 4 waves. Bijective XCD swizzle (grid % 8 == 0).
__global__ __launch_bounds__(256) void gemm_qkv_bf16(
    const u16* __restrict__ A, const u16* __restrict__ B,
    u16* __restrict__ C, int M, int N, int K) {
  __shared__ u16 As[128 * 32];
  __shared__ u16 Bs[128 * 32];
  const int t = threadIdx.x;
  const int l = t & 63, w = t >> 6;
  const int nbx = gridDim.x;
  const int fl = blockIdx.y * nbx + blockIdx.x;
  const int q8 = (nbx * gridDim.y) >> 3;
  const int fl2 = (fl & 7) * q8 + (fl >> 3);
  const int m0 = (fl2 / nbx) * 128, n0 = (fl2 % nbx) * 128;
  const int wm = (w >> 1) * 64, wn = (w & 1) * 64;

  f32x4 acc[4][4];
#pragma unroll
  for (int i = 0; i < 4; ++i)
#pragma unroll
    for (int j = 0; j < 4; ++j) acc[i][j] = (f32x4)0.f;

  const size_t Kb = (size_t)K * 2;
  const int o_lo = w * 1024 + l * 16;
  const int o_hi = 4096 + w * 1024 + l * 16;
  const int r_lo = o_lo >> 6, kb_lo = o_lo & 63;
  const int r_hi = o_hi >> 6, kb_hi = o_hi & 63;

  const char* Ap0 = (const char*)A + (size_t)(m0 + r_lo) * Kb + kb_lo;
  const char* Ap1 = (const char*)A + (size_t)(m0 + r_hi) * Kb + kb_hi;
  const char* Bp0 = (const char*)B + (size_t)(n0 + r_lo) * Kb + kb_lo;
  const char* Bp1 = (const char*)B + (size_t)(n0 + r_hi) * Kb + kb_hi;
  u16* AsB0 = As + (w * 1024) / 2;
  u16* AsB1 = As + (4096 + w * 1024) / 2;
  u16* BsB0 = Bs + (w * 1024) / 2;
  u16* BsB1 = Bs + (4096 + w * 1024) / 2;

  const int fr = l & 15, ko = (l >> 4) * 8;

  for (int k0 = 0; k0 < K; k0 += 32) {
    __syncthreads();
    gload_lds16(Ap0, AsB0);
    gload_lds16(Ap1, AsB1);
    gload_lds16(Bp0, BsB0);
    gload_lds16(Bp1, BsB1);
    Ap0 += 64; Ap1 += 64; Bp0 += 64; Bp1 += 64;
    __syncthreads();
    bf16x8 a[4], b[4];
#pragma unroll
    for (int m = 0; m < 4; ++m)
      a[m] = *(const bf16x8*)&As[(wm + m * 16 + fr) * 32 + ko];
#pragma unroll
    for (int n = 0; n < 4; ++n)
      b[n] = *(const bf16x8*)&Bs[(wn + n * 16 + fr) * 32 + ko];
#pragma unroll
    for (int m = 0; m < 4; ++m)
#pragma unroll
      for (int n = 0; n < 4; ++n)
        acc[m][n] = MFMA(a[m], b[n], acc[m][n]);
  }

  const int cr = (l >> 4) * 4, ccol = l & 15;
#pragma unroll
  for (int m = 0; m < 4; ++m)
#pragma unroll
    for (int n = 0; n < 4; ++n)
#pragma unroll
      for (int j = 0; j < 4; ++j)
        C[(size_t)(m0 + wm + m * 16 + cr + j) * N + (n0 + wn + n * 16 + ccol)] =
            f2bf(acc[m][n][j]);
}

// 64x64 tile, BK=32, 4 waves each 16(m)x64(n). Wo GEMM, bf16 out. XCD-swizzled.
__global__ __launch_bounds__(256) void gemm64_bf16(
    const u16* __restrict__ A, const u16* __restrict__ B,
    u16* __restrict__ C, int M, int N, int K) {
  __shared__ u16 As[64 * 32];
  __shared__ u16 Bs[64 * 32];
  const int t = threadIdx.x;
  const int l = t & 63, w = t >> 6;
  const int nbx = gridDim.x;
  const int fl = blockIdx.y * nbx + blockIdx.x;
  const int q8 = (nbx * gridDim.y) >> 3;
  const int fl2 = (fl & 7) * q8 + (fl >> 3);
  const int m0 = (fl2 / nbx) * 64, n0 = (fl2 % nbx) * 64;
  const int fr = l & 15, kg = l >> 4;
  const size_t Kb = (size_t)K * 2;
  const int o = t * 16, r = o >> 6, kb = o & 63;
  const char* Ap = (const char*)A + (size_t)(m0 + r) * Kb + kb;
  const char* Bp = (const char*)B + (size_t)(n0 + r) * Kb + kb;
  u16* AsB = As + (w * 1024) / 2;
  u16* BsB = Bs + (w * 1024) / 2;
  f32x4 acc[4];
#pragma unroll
  for (int i = 0; i < 4; ++i) acc[i] = (f32x4)0.f;
  for (int k0 = 0; k0 < K; k0 += 32) {
    __syncthreads();
    gload_lds16(Ap, AsB);
    gload_lds16(Bp, BsB);
    Ap += 64; Bp += 64;
    __syncthreads();
    bf16x8 a = *(const bf16x8*)&As[(16 * w + fr) * 32 + kg * 8];
#pragma unroll
    for (int nt = 0; nt < 4; ++nt) {
      bf16x8 b = *(const bf16x8*)&Bs[(16 * nt + fr) * 32 + kg * 8];
      acc[nt] = MFMA(a, b, acc[nt]);
    }
  }
#pragma unroll
  for (int nt = 0; nt < 4; ++nt)
#pragma unroll
    for (int reg = 0; reg < 4; ++reg)
      C[(size_t)(m0 + 16 * w + 4 * kg + reg) * N + (n0 + 16 * nt + fr)] =
          f2bf(acc[nt][reg]);
}

// DPFP for k (+v), bf16 proj: writes kf_t, kfT_t, vT_t fragment tiles.
__global__ __launch_bounds__(256) void dpfp_k64(
    const u16* __restrict__ proj, u16* __restrict__ kft,
    u16* __restrict__ kfTt, u16* __restrict__ vTt) {
  const int c = blockIdx.x, bn = blockIdx.y;
  const int b = bn >> 4, n = bn & 15;
  const int s0 = c * CHUNK;
  const int t = threadIdx.x;
  __shared__ float y[64][129];
  __shared__ float vs[64][65];
  const int j = t >> 2, dq = (t & 3) << 4;
  const u16* kp = proj + (size_t)((s0 + j) * BATCH + b) * 3072 + n * DHEAD + dq;
#pragma unroll
  for (int u = 0; u < 2; ++u) {
    ushort8 xv = *(const ushort8*)(kp + 1024 + 8 * u);   // k cols
    ushort8 vv = *(const ushort8*)(kp + 2048 + 8 * u);   // v cols
#pragma unroll
    for (int e = 0; e < 8; ++e) {
      float x = bf2f(xv[e]);
      int d = dq + 8 * u + e;
      y[j][d] = fmaxf(x, 0.f);
      y[j][64 + d] = fmaxf(-x, 0.f);
      vs[j][d] = bf2f(vv[e]);
    }
  }
  __syncthreads();
  const int fr = t & 15, kg = (t >> 4) & 3, l = t & 63;
  // kf_t tiles (rows s, cols f)
  {
    u16* base = kft + (size_t)bn * 589824;
#pragma unroll 2
    for (int it = 0; it < 12; ++it) {
      int tile = it * 4 + (t >> 6);
      int rT = tile / 12, cB = tile % 12;
      int sl = rT * 16 + fr;
      ushort8 o;
#pragma unroll
      for (int e = 0; e < 8; ++e) {
        int f = cB * 32 + kg * 8 + e, m = f & 127, sh = (f >> 7) + 1;
        o[e] = f2bf(y[sl][m] * y[sl][(m - sh) & 127]);
      }
      *(ushort8*)(base + ((size_t)(4 * c + rT) * 12 + cB) * 512 + l * 8) = o;
    }
  }
  // kfT_t tiles (rows f: 24 rT, cols s: this chunk covers cB = 2c, 2c+1)
  {
    u16* base = kfTt + (size_t)bn * 589824;
#pragma unroll 2
    for (int it = 0; it < 12; ++it) {
      int tile = it * 4 + (t >> 6);          // 0..47: rT*2 + cHalf
      int rT = tile >> 1, cHalf = tile & 1;
      int f = rT * 16 + fr, m = f & 127, sh = (f >> 7) + 1;
      int sb = cHalf * 32 + kg * 8;
      ushort8 o;
#pragma unroll
      for (int e = 0; e < 8; ++e)
        o[e] = f2bf(y[sb + e][m] * y[sb + e][(m - sh) & 127]);
      *(ushort8*)(base + ((size_t)rT * 48 + 2 * c + cHalf) * 512 + l * 8) = o;
    }
  }
  // vT_t tiles (rows d: 4 rT, cols s)
  {
    u16* base = vTt + (size_t)bn * 98304;
#pragma unroll
    for (int it = 0; it < 2; ++it) {
      int tile = it * 4 + (t >> 6);          // 0..7: rT*2 + cHalf
      int rT = tile >> 1, cHalf = tile & 1;
      int d = rT * 16 + fr;
      int sb = cHalf * 32 + kg * 8;
      ushort8 o;
#pragma unroll
      for (int e = 0; e < 8; ++e) o[e] = f2bf(vs[sb + e][d]);
      *(ushort8*)(base + ((size_t)rT * 48 + 2 * c + cHalf) * 512 + l * 8) = o;
    }
  }
}

// Fused chunk-KV + exclusive prefix scan (round-6/10 proven). 384 blocks.
__global__ __launch_bounds__(256) void chunk_kv_scan(
    const u16* __restrict__ kfTt, const u16* __restrict__ vTt,
    u16* __restrict__ kvswz, float* __restrict__ ksumst) {
  const int fl = blockIdx.x;
  const int fl2 = (fl & 7) * 48 + (fl >> 3);   // bijective, 384 % 8 == 0
  const int bn = fl2 / 12, ft2 = fl2 % 12;
  const int t = threadIdx.x, l = t & 63, w = t >> 6;
  const int fr = l & 15, kg = l >> 4;
  const u16* vt_base = vTt + (size_t)bn * 98304;
  const u16* kt_base = kfTt + (size_t)bn * 589824;

  __shared__ u16 Ys[64][40];   // prefix transpose staging

  f32x4 pacc0 = (f32x4)0.f, pacc1 = (f32x4)0.f;
  float pks = 0.f;

  for (int c = 0; c < NCHUNK; ++c) {
    f32x4 acc0 = (f32x4)0.f, acc1 = (f32x4)0.f;
    float ksp = 0.f;
#pragma unroll
    for (int ksi = 0; ksi < 2; ++ksi) {
      bf16x8 a = *(const bf16x8*)(vt_base + ((size_t)w * 48 + 2 * c + ksi) * 512 + l * 8);
      const u16* bp0 = kt_base + ((size_t)(2 * ft2 + 0) * 48 + 2 * c + ksi) * 512 + l * 8;
      const u16* bp1 = kt_base + ((size_t)(2 * ft2 + 1) * 48 + 2 * c + ksi) * 512 + l * 8;
      bf16x8 b0 = *(const bf16x8*)bp0;
      bf16x8 b1 = *(const bf16x8*)bp1;
      if (w == 0) {
        ushort8 raw = *(const ushort8*)bp0;
#pragma unroll
        for (int e = 0; e < 8; ++e) ksp += bf2f(raw[e]);
      } else if (w == 1) {
        ushort8 raw = *(const ushort8*)bp1;
#pragma unroll
        for (int e = 0; e < 8; ++e) ksp += bf2f(raw[e]);
      }
      acc0 = MFMA(a, b0, acc0);
      acc1 = MFMA(a, b1, acc1);
    }
    __syncthreads();
#pragma unroll
    for (int reg = 0; reg < 4; ++reg) {
      Ys[16 * w + 4 * kg + reg][fr] = f2bf(pacc0[reg]);
      Ys[16 * w + 4 * kg + reg][16 + fr] = f2bf(pacc1[reg]);
    }
    __syncthreads();
    {
      ushort8 o = *(const ushort8*)&Ys[w * 16 + fr][kg * 8];
      *(ushort8*)(kvswz + (size_t)(bn * NCHUNK + c) * 24576 +
                  (size_t)(w * 12 + ft2) * 512 + l * 8) = o;
    }
    if (w < 2) {
      float x = ksp;
      x += __shfl_xor(x, 16);
      x += __shfl_xor(x, 32);
      if (kg == 0)
        ksumst[(size_t)(bn * NCHUNK + c) * FDIM + ft2 * 32 + w * 16 + fr] = pks;
      pks += x;
    }
    pacc0 += acc0;
    pacc1 += acc1;
  }
}

// Fused attention: A-fragments (q-features) built in-register from LDS y_q;
// B-operands stream from kft / kvswz / vTt fragment tiles. Grid (c, bn).
__global__ __launch_bounds__(256) void attn_mfma(
    const u16* __restrict__ proj, const u16* __restrict__ kft,
    const u16* __restrict__ vTt, const u16* __restrict__ kvswz,
    const float* __restrict__ kspre, u16* __restrict__ attnvec) {
  const int c = blockIdx.x, bn = blockIdx.y;
  const int b = bn >> 4, n = bn & 15;
  const int s0 = c * CHUNK;
  const int t = threadIdx.x, l = t & 63, w = t >> 6;
  const int fr = l & 15, kg = l >> 4;

  const u16* kbase = kft + (size_t)bn * 589824;
  const u16* vbase = vTt + (size_t)bn * 98304;
  const u16* kvbase = kvswz + (size_t)(bn * NCHUNK + c) * 24576;
  const float* ksp = kspre + (size_t)(bn * NCHUNK + c) * FDIM;

  __shared__ u16 y_q[64][132];   // relu pairs, bf16; pitch 132 -> <=2-way banks
  __shared__ u16 Sb[64][70];

  // stage q relu-pairs via bit-ops (input already bf16)
  {
    const int j = t >> 2, dq = (t & 3) << 4;
    const u16* qp = proj + (size_t)((s0 + j) * BATCH + b) * 3072 + n * DHEAD + dq;
#pragma unroll
    for (int u = 0; u < 2; ++u) {
      ushort8 xv = *(const ushort8*)(qp + 8 * u);
      ushort8 pos, neg;
#pragma unroll
      for (int e = 0; e < 8; ++e) {
        u16 x = xv[e];
        bool sn = (x & 0x8000u) != 0;
        pos[e] = sn ? (u16)0 : x;
        neg[e] = sn ? (u16)(x & 0x7fffu) : (u16)0;
      }
      *(ushort8*)&y_q[j][dq + 8 * u] = pos;
      *(ushort8*)&y_q[j][64 + dq + 8 * u] = neg;
    }
  }
  __syncthreads();

  f32x4 acc[9];
#pragma unroll
  for (int i = 0; i < 9; ++i) acc[i] = (f32x4)0.f;

  const u16* yqrow = &y_q[16 * w + fr][0];

#pragma unroll
  for (int shb = 0; shb < 3; ++shb) {
#pragma unroll
    for (int q4 = 0; q4 < 4; ++q4) {
      const int cB = shb * 4 + q4;
      const int m = q4 * 32 + kg * 8;
      bf16x8 a = feat_frag(yqrow, m, shb + 1);
#pragma unroll
      for (int nt = 0; nt < 4; ++nt) {
        bf16x8 bfrag = *(const bf16x8*)(kbase + ((size_t)(4 * c + nt) * 12 + cB) * 512 + l * 8);
        acc[nt] = MFMA(a, bfrag, acc[nt]);
      }
#pragma unroll
      for (int nt = 0; nt < 4; ++nt) {
        bf16x8 bfrag = *(const bf16x8*)(kvbase + ((size_t)nt * 12 + cB) * 512 + l * 8);
        acc[4 + nt] = MFMA(a, bfrag, acc[4 + nt]);
      }
      // den B-tile: row fr==0 holds prefixed ksum, rest zero
      ushort8 bd = {0, 0, 0, 0, 0, 0, 0, 0};
      if (fr == 0) {
#pragma unroll
        for (int e = 0; e < 8; ++e) bd[e] = f2bf(ksp[cB * 32 + kg * 8 + e]);
      }
      union { ushort8 u; bf16x8 v; } cu;
      cu.u = bd;
      acc[8] = MFMA(a, cu.v, acc[8]);
    }
  }

  // mask (j>i -> 0) + intra rowsum (butterfly over fr lanes) + S -> LDS bf16
  float rsum[4];
#pragma unroll
  for (int reg = 0; reg < 4; ++reg) {
    int i = 16 * w + 4 * kg + reg;
    float r = 0.f;
#pragma unroll
    for (int nt = 0; nt < 4; ++nt) {
      int jj = 16 * nt + fr;
      float sval = (jj <= i) ? acc[nt][reg] : 0.f;
      acc[nt][reg] = sval;
      r += sval;
    }
    r += __shfl_xor(r, 1); r += __shfl_xor(r, 2);
    r += __shfl_xor(r, 4); r += __shfl_xor(r, 8);
    rsum[reg] = r;
  }
#pragma unroll
  for (int nt = 0; nt < 4; ++nt)
#pragma unroll
    for (int reg = 0; reg < 4; ++reg)
      Sb[16 * w + 4 * kg + reg][16 * nt + fr] = f2bf(acc[nt][reg]);

  __syncthreads();

  // PV: acc[4..7] += S * vT
#pragma unroll
  for (int ksi = 0; ksi < 2; ++ksi) {
    const int ko = ksi * 32 + kg * 8;
    bf16x8 a = *(const bf16x8*)&Sb[16 * w + fr][ko];
#pragma unroll
    for (int nt = 0; nt < 4; ++nt) {
      bf16x8 bfrag = *(const bf16x8*)(vbase + ((size_t)nt * 48 + 2 * c + ksi) * 512 + l * 8);
      acc[4 + nt] = MFMA(a, bfrag, acc[4 + nt]);
    }
  }

  // normalize + store; den for row i held by lane (kg, fr=0) in acc[8]
#pragma unroll
  for (int reg = 0; reg < 4; ++reg) {
    int i = 16 * w + 4 * kg + reg;
    float dinter = __shfl(acc[8][reg], l & 48);
    float den = rsum[reg] + dinter;
    float sc = SCALE_F / (SCALE_F * den + EPS_D);
    int rowg = (s0 + i) * BATCH + b;
    u16* orow = attnvec + (size_t)rowg * DMODEL + n * DHEAD;
#pragma unroll
    for (int nt = 0; nt < 4; ++nt)
      orow[16 * nt + fr] = f2bf(acc[4 + nt][reg] * sc);
  }
}

// out = LN(h + attn_out) * gamma + beta  (attn_out now bf16)
__global__ __launch_bounds__(256) void ln_kernel(
    const float* __restrict__ h, const u16* __restrict__ ao,
    const float* __restrict__ gamma, const float* __restrict__ beta,
    float* __restrict__ out) {
  const int r = blockIdx.x, t = threadIdx.x;
  const float* hr = h + (size_t)r * DMODEL;
  const u16* ar = ao + (size_t)r * DMODEL;
  float4 xh = *(const float4*)(hr + t * 4);
  ushort4 xa = *(const ushort4*)(ar + t * 4);
  float4 x = {xh.x + bf2f(xa.x), xh.y + bf2f(xa.y),
              xh.z + bf2f(xa.z), xh.w + bf2f(xa.w)};
  float sum = x.x + x.y + x.z + x.w;
  float sq = x.x * x.x + x.y * x.y + x.z * x.z + x.w * x.w;
#pragma unroll
  for (int o = 32; o >= 1; o >>= 1) {
    sum += __shfl_xor(sum, o);
    sq += __shfl_xor(sq, o);
  }
  __shared__ float s_sum[4], s_sq[4];
  int w = t >> 6;
  if ((t & 63) == 0) { s_sum[w] = sum; s_sq[w] = sq; }
  __syncthreads();
  sum = s_sum[0] + s_sum[1] + s_sum[2] + s_sum[3];
  sq = s_sq[0] + s_sq[1] + s_sq[2] + s_sq[3];
  float mean = sum * (1.0f / DMODEL);
  float var = sq * (1.0f / DMODEL) - mean * mean;
  float rstd = rsqrtf(var + EPS_LN);
  float4 g = *(const float4*)(gamma + t * 4);
  float4 bb = *(const float4*)(beta + t * 4);
  float4 o4 = {g.x * (x.x - mean) * rstd + bb.x,
               g.y * (x.y - mean) * rstd + bb.y,
               g.z * (x.z - mean) * rstd + bb.z,
               g.w * (x.w - mean) * rstd + bb.w};
  *(float4*)(out + (size_t)r * DMODEL + t * 4) = o4;
}

extern "C" void kernel_launch(void* const* d_in, const int* in_sizes, int n_in,
                              void* d_out, int out_size, void* d_ws, size_t ws_size,
                              hipStream_t stream) {
  const float* h = (const float*)d_in[0];
  const float* Wq = (const float*)d_in[1];
  const float* Wkv = (const float*)d_in[2];
  const float* Wo = (const float*)d_in[3];
  const float* gamma = (const float*)d_in[4];
  const float* beta = (const float*)d_in[5];
  float* out = (float*)d_out;

  // flat slabs (u16-elem offsets), total ~162 MB, no overlays
  u16* proj = (u16*)d_ws;                        // [3072][3072] bf16
  u16* kft = proj + 9437184;                     // [32]*589824 u16
  u16* kfTt = kft + 18874368;                    // [32]*589824 u16
  u16* vTt = kfTt + 18874368;                    // [32]*98304 u16
  u16* kvswz = vTt + 3145728;                    // [32][24][4][12][512] u16
  float* ksumst = (float*)(kvswz + 18874368);    // [32][24][384] f32
  u16* Wo_bf = (u16*)(ksumst + 294912);          // [1024][1024] u16
  u16* h_bf = Wo_bf + 1048576;                   // [3072][1024] u16
  u16* Wqkv_bf = h_bf + 3145728;                 // [3072][1024] u16
  u16* attnvec = Wqkv_bf + 3145728;              // [3072][1024] u16
  u16* attnout = attnvec + 3145728;              // [3072][1024] u16

  hipLaunchKernelGGL(cvt_all, dim3(7168), dim3(256), 0, stream,
                     h, Wq, Wkv, Wo, h_bf, Wqkv_bf, Wo_bf);
  hipLaunchKernelGGL(gemm_qkv_bf16, dim3(24, 24), dim3(256), 0, stream,
                     h_bf, Wqkv_bf, proj, ROWS, 3072, 1024);
  hipLaunchKernelGGL(dpfp_k64, dim3(24, 32), dim3(256), 0, stream,
                     proj, kft, kfTt, vTt);
  hipLaunchKernelGGL(chunk_kv_scan, dim3(384), dim3(256), 0, stream,
                     kfTt, vTt, kvswz, ksumst);
  hipLaunchKernelGGL(attn_mfma, dim3(24, 32), dim3(256), 0, stream,
                     proj, kft, vTt, kvswz, ksumst, attnvec);
  hipLaunchKernelGGL(gemm64_bf16, dim3(16, 48), dim3(256), 0, stream,
                     attnvec, Wo_bf, attnout, ROWS, 1024, 1024);
  hipLaunchKernelGGL(ln_kernel, dim3(3072), dim3(256), 0, stream,
                     h, attnout, gamma, beta, out);
}

// Round 12
// 147.663 us; speedup vs baseline: 1.0131x; 1.0131x over previous
//
#include <hip/hip_runtime.h>
#include <hip/hip_bf16.h>

#define S_LEN 1536
#define BATCH 2
#define DMODEL 1024
#define NHEAD 16
#define DHEAD 64
#define FDIM 384          // 2*DHEAD*N_ROLL
#define CHUNK 64
#define NCHUNK 24         // S_LEN / CHUNK
#define ROWS (S_LEN*BATCH)
#define SCALE_F 0.125f
#define EPS_D 1e-5f
#define EPS_LN 1e-5f

typedef unsigned short u16;
typedef __attribute__((ext_vector_type(8))) __bf16 bf16x8;
typedef __attribute__((ext_vector_type(8))) unsigned short ushort8;
typedef __attribute__((ext_vector_type(4))) float f32x4;

static __device__ __forceinline__ float bf2f(u16 a) {
  return __uint_as_float(((unsigned)a) << 16);
}
static __device__ __forceinline__ u16 f2bf(float x) {
  unsigned u = __float_as_uint(x);
  unsigned r = (u + 0x7FFFu + ((u >> 16) & 1u)) >> 16;
  return (u16)r;
}
static __device__ __forceinline__ void gload_lds16(const void* g, void* l) {
  __builtin_amdgcn_global_load_lds(
      (const __attribute__((address_space(1))) void*)g,
      (__attribute__((address_space(3))) void*)l, 16, 0, 0);
}
#define MFMA(a, b, c) __builtin_amdgcn_mfma_f32_16x16x32_bf16(a, b, c, 0, 0, 0)

static __device__ __forceinline__ void unpk(unsigned u, float& lo, float& hi) {
  lo = __uint_as_float(u << 16);
  hi = __uint_as_float(u & 0xffff0000u);
}

// Build feature A-fragment octet f=[m..m+8) for one y-row (s fixed):
// feat[e] = y[m+e] * y[(m+e-SH)&127]. SH constant-folds (callers unroll).
static __device__ __forceinline__ bf16x8 feat_frag(
    const u16* __restrict__ yrow, int m, int SH) {
  union U { ushort8 v; unsigned u[4]; };
  U y1, y0;
  y1.v = *(const ushort8*)(yrow + m);
  y0.v = *(const ushort8*)(yrow + ((m - 8) & 127));
  unsigned seq2 = y0.u[2], seq3 = y0.u[3];
  unsigned seq4 = y1.u[0], seq5 = y1.u[1], seq6 = y1.u[2], seq7 = y1.u[3];
  unsigned y2u[4];
  if (SH == 2) {                     // byte offset 12: pure dword select
    y2u[0] = seq3; y2u[1] = seq4; y2u[2] = seq5; y2u[3] = seq6;
  } else if (SH == 1) {              // byte offset 14
    y2u[0] = (seq3 >> 16) | (seq4 << 16);
    y2u[1] = (seq4 >> 16) | (seq5 << 16);
    y2u[2] = (seq5 >> 16) | (seq6 << 16);
    y2u[3] = (seq6 >> 16) | (seq7 << 16);
  } else {                           // SH==3, byte offset 10
    y2u[0] = (seq2 >> 16) | (seq3 << 16);
    y2u[1] = (seq3 >> 16) | (seq4 << 16);
    y2u[2] = (seq4 >> 16) | (seq5 << 16);
    y2u[3] = (seq5 >> 16) | (seq6 << 16);
  }
  bf16x8 out;
#pragma unroll
  for (int i = 0; i < 4; ++i) {
    float a0, a1, b0, b1;
    unpk(y1.u[i], a0, a1);
    unpk(y2u[i], b0, b1);
    out[2 * i] = (__bf16)(a0 * b0);
    out[2 * i + 1] = (__bf16)(a1 * b1);
  }
  return out;
}

// Fragment-tile layout: buffer [R][C] stored as [R/16][C/32][64][8] u16,
// lane l = kg*16+fr holds (row rT*16+fr, cols cB*32+kg*8 .. +8).

// One fused f32->bf16 convert for h, Wq, Wkv, Wo (quad-granular regions).
__global__ __launch_bounds__(256) void cvt_all(
    const float* __restrict__ h, const float* __restrict__ Wq,
    const float* __restrict__ Wkv, const float* __restrict__ Wo,
    u16* __restrict__ h_bf, u16* __restrict__ Wqkv_bf, u16* __restrict__ Wo_bf) {
  int i = blockIdx.x * 256 + threadIdx.x;   // quad index, 1835008 total
  const float* src; u16* dst; int j;
  if (i < 786432) { src = h; dst = h_bf; j = i; }
  else if (i < 1048576) { src = Wq; dst = Wqkv_bf; j = i - 786432; }
  else if (i < 1572864) { src = Wkv; dst = Wqkv_bf + 1048576; j = i - 1048576; }
  else { src = Wo; dst = Wo_bf; j = i - 1572864; }
  float4 v = ((const float4*)src)[j];
  ushort4 o = {f2bf(v.x), f2bf(v.y), f2bf(v.z), f2bf(v.w)};
  ((ushort4*)dst)[j] = o;
}

// QKV projection: C[M][N] = A[M][K]*B[N][K]^T, bf16 in, bf16 out.
// 128x64 tile, BK=32, 4 waves (each 32m x 64n). Grid flat 1152 blocks
// (= 4.5/CU, double the 128x128 grid) for latency hiding; bijective XCD
// swizzle. LDS 12KB.
__global__ __launch_bounds__(256) void gemm_qkv_bf16(
    const u16* __restrict__ A, const u16* __restrict__ B,
    u16* __restrict__ C, int M, int N, int K) {
  __shared__ u16 As[128 * 32];
  __shared__ u16 Bs[64 * 32];
  const int t = threadIdx.x;
  const int l = t & 63, w = t >> 6;
  const int nbx = N >> 6;                     // N/64 col-tiles
  const int fl = blockIdx.x;
  const int q8 = gridDim.x >> 3;
  const int fl2 = (fl & 7) * q8 + (fl >> 3);  // bijective, grid % 8 == 0
  const int m0 = (fl2 / nbx) * 128, n0 = (fl2 % nbx) * 64;

  f32x4 acc[2][4];
#pragma unroll
  for (int i = 0; i < 2; ++i)
#pragma unroll
    for (int j = 0; j < 4; ++j) acc[i][j] = (f32x4)0.f;

  const size_t Kb = (size_t)K * 2;
  // A staging: 8KB in two rounds of t*16; B staging: 4KB in one round.
  const int oA_lo = t * 16, oA_hi = 4096 + t * 16;
  const int rA_lo = oA_lo >> 6, kbA_lo = oA_lo & 63;
  const int rA_hi = oA_hi >> 6, kbA_hi = oA_hi & 63;
  const int oB = t * 16, rB = oB >> 6, kbB = oB & 63;

  const char* Ap0 = (const char*)A + (size_t)(m0 + rA_lo) * Kb + kbA_lo;
  const char* Ap1 = (const char*)A + (size_t)(m0 + rA_hi) * Kb + kbA_hi;
  const char* Bp0 = (const char*)B + (size_t)(n0 + rB) * Kb + kbB;
  u16* AsB0 = As + (w * 1024) / 2;            // wave-uniform LDS bases
  u16* AsB1 = As + (4096 + w * 1024) / 2;
  u16* BsB0 = Bs + (w * 1024) / 2;

  const int fr = l & 15, ko = (l >> 4) * 8;

  for (int k0 = 0; k0 < K; k0 += 32) {
    __syncthreads();
    gload_lds16(Ap0, AsB0);
    gload_lds16(Ap1, AsB1);
    gload_lds16(Bp0, BsB0);
    Ap0 += 64; Ap1 += 64; Bp0 += 64;
    __syncthreads();
    bf16x8 a[2], b[4];
#pragma unroll
    for (int mi = 0; mi < 2; ++mi)
      a[mi] = *(const bf16x8*)&As[(w * 32 + mi * 16 + fr) * 32 + ko];
#pragma unroll
    for (int nt = 0; nt < 4; ++nt)
      b[nt] = *(const bf16x8*)&Bs[(nt * 16 + fr) * 32 + ko];
#pragma unroll
    for (int mi = 0; mi < 2; ++mi)
#pragma unroll
      for (int nt = 0; nt < 4; ++nt)
        acc[mi][nt] = MFMA(a[mi], b[nt], acc[mi][nt]);
  }

  const int cr = (l >> 4) * 4, ccol = l & 15;
#pragma unroll
  for (int mi = 0; mi < 2; ++mi)
#pragma unroll
    for (int nt = 0; nt < 4; ++nt)
#pragma unroll
      for (int j = 0; j < 4; ++j)
        C[(size_t)(m0 + w * 32 + mi * 16 + cr + j) * N + (n0 + nt * 16 + ccol)] =
            f2bf(acc[mi][nt][j]);
}

// 64x64 tile, BK=32, 4 waves each 16(m)x64(n). Wo GEMM, bf16 out. XCD-swizzled.
__global__ __launch_bounds__(256) void gemm64_bf16(
    const u16* __restrict__ A, const u16* __restrict__ B,
    u16* __restrict__ C, int M, int N, int K) {
  __shared__ u16 As[64 * 32];
  __shared__ u16 Bs[64 * 32];
  const int t = threadIdx.x;
  const int l = t & 63, w = t >> 6;
  const int nbx = gridDim.x;
  const int fl = blockIdx.y * nbx + blockIdx.x;
  const int q8 = (nbx * gridDim.y) >> 3;
  const int fl2 = (fl & 7) * q8 + (fl >> 3);
  const int m0 = (fl2 / nbx) * 64, n0 = (fl2 % nbx) * 64;
  const int fr = l & 15, kg = l >> 4;
  const size_t Kb = (size_t)K * 2;
  const int o = t * 16, r = o >> 6, kb = o & 63;
  const char* Ap = (const char*)A + (size_t)(m0 + r) * Kb + kb;
  const char* Bp = (const char*)B + (size_t)(n0 + r) * Kb + kb;
  u16* AsB = As + (w * 1024) / 2;
  u16* BsB = Bs + (w * 1024) / 2;
  f32x4 acc[4];
#pragma unroll
  for (int i = 0; i < 4; ++i) acc[i] = (f32x4)0.f;
  for (int k0 = 0; k0 < K; k0 += 32) {
    __syncthreads();
    gload_lds16(Ap, AsB);
    gload_lds16(Bp, BsB);
    Ap += 64; Bp += 64;
    __syncthreads();
    bf16x8 a = *(const bf16x8*)&As[(16 * w + fr) * 32 + kg * 8];
#pragma unroll
    for (int nt = 0; nt < 4; ++nt) {
      bf16x8 b = *(const bf16x8*)&Bs[(16 * nt + fr) * 32 + kg * 8];
      acc[nt] = MFMA(a, b, acc[nt]);
    }
  }
#pragma unroll
  for (int nt = 0; nt < 4; ++nt)
#pragma unroll
    for (int reg = 0; reg < 4; ++reg)
      C[(size_t)(m0 + 16 * w + 4 * kg + reg) * N + (n0 + 16 * nt + fr)] =
          f2bf(acc[nt][reg]);
}

// DPFP for k (+v), bf16 proj: writes kf_t, kfT_t, vT_t fragment tiles.
__global__ __launch_bounds__(256) void dpfp_k64(
    const u16* __restrict__ proj, u16* __restrict__ kft,
    u16* __restrict__ kfTt, u16* __restrict__ vTt) {
  const int c = blockIdx.x, bn = blockIdx.y;
  const int b = bn >> 4, n = bn & 15;
  const int s0 = c * CHUNK;
  const int t = threadIdx.x;
  __shared__ float y[64][129];
  __shared__ float vs[64][65];
  const int j = t >> 2, dq = (t & 3) << 4;
  const u16* kp = proj + (size_t)((s0 + j) * BATCH + b) * 3072 + n * DHEAD + dq;
#pragma unroll
  for (int u = 0; u < 2; ++u) {
    ushort8 xv = *(const ushort8*)(kp + 1024 + 8 * u);   // k cols
    ushort8 vv = *(const ushort8*)(kp + 2048 + 8 * u);   // v cols
#pragma unroll
    for (int e = 0; e < 8; ++e) {
      float x = bf2f(xv[e]);
      int d = dq + 8 * u + e;
      y[j][d] = fmaxf(x, 0.f);
      y[j][64 + d] = fmaxf(-x, 0.f);
      vs[j][d] = bf2f(vv[e]);
    }
  }
  __syncthreads();
  const int fr = t & 15, kg = (t >> 4) & 3, l = t & 63;
  // kf_t tiles (rows s, cols f)
  {
    u16* base = kft + (size_t)bn * 589824;
#pragma unroll 2
    for (int it = 0; it < 12; ++it) {
      int tile = it * 4 + (t >> 6);
      int rT = tile / 12, cB = tile % 12;
      int sl = rT * 16 + fr;
      ushort8 o;
#pragma unroll
      for (int e = 0; e < 8; ++e) {
        int f = cB * 32 + kg * 8 + e, m = f & 127, sh = (f >> 7) + 1;
        o[e] = f2bf(y[sl][m] * y[sl][(m - sh) & 127]);
      }
      *(ushort8*)(base + ((size_t)(4 * c + rT) * 12 + cB) * 512 + l * 8) = o;
    }
  }
  // kfT_t tiles (rows f: 24 rT, cols s: this chunk covers cB = 2c, 2c+1)
  {
    u16* base = kfTt + (size_t)bn * 589824;
#pragma unroll 2
    for (int it = 0; it < 12; ++it) {
      int tile = it * 4 + (t >> 6);          // 0..47: rT*2 + cHalf
      int rT = tile >> 1, cHalf = tile & 1;
      int f = rT * 16 + fr, m = f & 127, sh = (f >> 7) + 1;
      int sb = cHalf * 32 + kg * 8;
      ushort8 o;
#pragma unroll
      for (int e = 0; e < 8; ++e)
        o[e] = f2bf(y[sb + e][m] * y[sb + e][(m - sh) & 127]);
      *(ushort8*)(base + ((size_t)rT * 48 + 2 * c + cHalf) * 512 + l * 8) = o;
    }
  }
  // vT_t tiles (rows d: 4 rT, cols s)
  {
    u16* base = vTt + (size_t)bn * 98304;
#pragma unroll
    for (int it = 0; it < 2; ++it) {
      int tile = it * 4 + (t >> 6);          // 0..7: rT*2 + cHalf
      int rT = tile >> 1, cHalf = tile & 1;
      int d = rT * 16 + fr;
      int sb = cHalf * 32 + kg * 8;
      ushort8 o;
#pragma unroll
      for (int e = 0; e < 8; ++e) o[e] = f2bf(vs[sb + e][d]);
      *(ushort8*)(base + ((size_t)rT * 48 + 2 * c + cHalf) * 512 + l * 8) = o;
    }
  }
}

// Fused chunk-KV + exclusive prefix scan (round-6/10 proven). 384 blocks.
__global__ __launch_bounds__(256) void chunk_kv_scan(
    const u16* __restrict__ kfTt, const u16* __restrict__ vTt,
    u16* __restrict__ kvswz, float* __restrict__ ksumst) {
  const int fl = blockIdx.x;
  const int fl2 = (fl & 7) * 48 + (fl >> 3);   // bijective, 384 % 8 == 0
  const int bn = fl2 / 12, ft2 = fl2 % 12;
  const int t = threadIdx.x, l = t & 63, w = t >> 6;
  const int fr = l & 15, kg = l >> 4;
  const u16* vt_base = vTt + (size_t)bn * 98304;
  const u16* kt_base = kfTt + (size_t)bn * 589824;

  __shared__ u16 Ys[64][40];   // prefix transpose staging

  f32x4 pacc0 = (f32x4)0.f, pacc1 = (f32x4)0.f;
  float pks = 0.f;

  for (int c = 0; c < NCHUNK; ++c) {
    f32x4 acc0 = (f32x4)0.f, acc1 = (f32x4)0.f;
    float ksp = 0.f;
#pragma unroll
    for (int ksi = 0; ksi < 2; ++ksi) {
      bf16x8 a = *(const bf16x8*)(vt_base + ((size_t)w * 48 + 2 * c + ksi) * 512 + l * 8);
      const u16* bp0 = kt_base + ((size_t)(2 * ft2 + 0) * 48 + 2 * c + ksi) * 512 + l * 8;
      const u16* bp1 = kt_base + ((size_t)(2 * ft2 + 1) * 48 + 2 * c + ksi) * 512 + l * 8;
      bf16x8 b0 = *(const bf16x8*)bp0;
      bf16x8 b1 = *(const bf16x8*)bp1;
      if (w == 0) {
        ushort8 raw = *(const ushort8*)bp0;
#pragma unroll
        for (int e = 0; e < 8; ++e) ksp += bf2f(raw[e]);
      } else if (w == 1) {
        ushort8 raw = *(const ushort8*)bp1;
#pragma unroll
        for (int e = 0; e < 8; ++e) ksp += bf2f(raw[e]);
      }
      acc0 = MFMA(a, b0, acc0);
      acc1 = MFMA(a, b1, acc1);
    }
    __syncthreads();
#pragma unroll
    for (int reg = 0; reg < 4; ++reg) {
      Ys[16 * w + 4 * kg + reg][fr] = f2bf(pacc0[reg]);
      Ys[16 * w + 4 * kg + reg][16 + fr] = f2bf(pacc1[reg]);
    }
    __syncthreads();
    {
      ushort8 o = *(const ushort8*)&Ys[w * 16 + fr][kg * 8];
      *(ushort8*)(kvswz + (size_t)(bn * NCHUNK + c) * 24576 +
                  (size_t)(w * 12 + ft2) * 512 + l * 8) = o;
    }
    if (w < 2) {
      float x = ksp;
      x += __shfl_xor(x, 16);
      x += __shfl_xor(x, 32);
      if (kg == 0)
        ksumst[(size_t)(bn * NCHUNK + c) * FDIM + ft2 * 32 + w * 16 + fr] = pks;
      pks += x;
    }
    pacc0 += acc0;
    pacc1 += acc1;
  }
}

// Fused attention: A-fragments (q-features) built in-register from LDS y_q;
// B-operands stream from kft / kvswz / vTt fragment tiles. Grid (c, bn).
__global__ __launch_bounds__(256) void attn_mfma(
    const u16* __restrict__ proj, const u16* __restrict__ kft,
    const u16* __restrict__ vTt, const u16* __restrict__ kvswz,
    const float* __restrict__ kspre, u16* __restrict__ attnvec) {
  const int c = blockIdx.x, bn = blockIdx.y;
  const int b = bn >> 4, n = bn & 15;
  const int s0 = c * CHUNK;
  const int t = threadIdx.x, l = t & 63, w = t >> 6;
  const int fr = l & 15, kg = l >> 4;

  const u16* kbase = kft + (size_t)bn * 589824;
  const u16* vbase = vTt + (size_t)bn * 98304;
  const u16* kvbase = kvswz + (size_t)(bn * NCHUNK + c) * 24576;
  const float* ksp = kspre + (size_t)(bn * NCHUNK + c) * FDIM;

  __shared__ u16 y_q[64][132];   // relu pairs, bf16; pitch 132 -> <=2-way banks
  __shared__ u16 Sb[64][70];

  // stage q relu-pairs via bit-ops (input already bf16)
  {
    const int j = t >> 2, dq = (t & 3) << 4;
    const u16* qp = proj + (size_t)((s0 + j) * BATCH + b) * 3072 + n * DHEAD + dq;
#pragma unroll
    for (int u = 0; u < 2; ++u) {
      ushort8 xv = *(const ushort8*)(qp + 8 * u);
      ushort8 pos, neg;
#pragma unroll
      for (int e = 0; e < 8; ++e) {
        u16 x = xv[e];
        bool sn = (x & 0x8000u) != 0;
        pos[e] = sn ? (u16)0 : x;
        neg[e] = sn ? (u16)(x & 0x7fffu) : (u16)0;
      }
      *(ushort8*)&y_q[j][dq + 8 * u] = pos;
      *(ushort8*)&y_q[j][64 + dq + 8 * u] = neg;
    }
  }
  __syncthreads();

  f32x4 acc[9];
#pragma unroll
  for (int i = 0; i < 9; ++i) acc[i] = (f32x4)0.f;

  const u16* yqrow = &y_q[16 * w + fr][0];

#pragma unroll
  for (int shb = 0; shb < 3; ++shb) {
#pragma unroll
    for (int q4 = 0; q4 < 4; ++q4) {
      const int cB = shb * 4 + q4;
      const int m = q4 * 32 + kg * 8;
      bf16x8 a = feat_frag(yqrow, m, shb + 1);
#pragma unroll
      for (int nt = 0; nt < 4; ++nt) {
        bf16x8 bfrag = *(const bf16x8*)(kbase + ((size_t)(4 * c + nt) * 12 + cB) * 512 + l * 8);
        acc[nt] = MFMA(a, bfrag, acc[nt]);
      }
#pragma unroll
      for (int nt = 0; nt < 4; ++nt) {
        bf16x8 bfrag = *(const bf16x8*)(kvbase + ((size_t)nt * 12 + cB) * 512 + l * 8);
        acc[4 + nt] = MFMA(a, bfrag, acc[4 + nt]);
      }
      // den B-tile: row fr==0 holds prefixed ksum, rest zero
      ushort8 bd = {0, 0, 0, 0, 0, 0, 0, 0};
      if (fr == 0) {
#pragma unroll
        for (int e = 0; e < 8; ++e) bd[e] = f2bf(ksp[cB * 32 + kg * 8 + e]);
      }
      union { ushort8 u; bf16x8 v; } cu;
      cu.u = bd;
      acc[8] = MFMA(a, cu.v, acc[8]);
    }
  }

  // mask (j>i -> 0) + intra rowsum (butterfly over fr lanes) + S -> LDS bf16
  float rsum[4];
#pragma unroll
  for (int reg = 0; reg < 4; ++reg) {
    int i = 16 * w + 4 * kg + reg;
    float r = 0.f;
#pragma unroll
    for (int nt = 0; nt < 4; ++nt) {
      int jj = 16 * nt + fr;
      float sval = (jj <= i) ? acc[nt][reg] : 0.f;
      acc[nt][reg] = sval;
      r += sval;
    }
    r += __shfl_xor(r, 1); r += __shfl_xor(r, 2);
    r += __shfl_xor(r, 4); r += __shfl_xor(r, 8);
    rsum[reg] = r;
  }
#pragma unroll
  for (int nt = 0; nt < 4; ++nt)
#pragma unroll
    for (int reg = 0; reg < 4; ++reg)
      Sb[16 * w + 4 * kg + reg][16 * nt + fr] = f2bf(acc[nt][reg]);

  __syncthreads();

  // PV: acc[4..7] += S * vT
#pragma unroll
  for (int ksi = 0; ksi < 2; ++ksi) {
    const int ko = ksi * 32 + kg * 8;
    bf16x8 a = *(const bf16x8*)&Sb[16 * w + fr][ko];
#pragma unroll
    for (int nt = 0; nt < 4; ++nt) {
      bf16x8 bfrag = *(const bf16x8*)(vbase + ((size_t)nt * 48 + 2 * c + ksi) * 512 + l * 8);
      acc[4 + nt] = MFMA(a, bfrag, acc[4 + nt]);
    }
  }

  // normalize + store; den for row i held by lane (kg, fr=0) in acc[8]
#pragma unroll
  for (int reg = 0; reg < 4; ++reg) {
    int i = 16 * w + 4 * kg + reg;
    float dinter = __shfl(acc[8][reg], l & 48);
    float den = rsum[reg] + dinter;
    float sc = SCALE_F / (SCALE_F * den + EPS_D);
    int rowg = (s0 + i) * BATCH + b;
    u16* orow = attnvec + (size_t)rowg * DMODEL + n * DHEAD;
#pragma unroll
    for (int nt = 0; nt < 4; ++nt)
      orow[16 * nt + fr] = f2bf(acc[4 + nt][reg] * sc);
  }
}

// out = LN(h + attn_out) * gamma + beta  (attn_out bf16)
__global__ __launch_bounds__(256) void ln_kernel(
    const float* __restrict__ h, const u16* __restrict__ ao,
    const float* __restrict__ gamma, const float* __restrict__ beta,
    float* __restrict__ out) {
  const int r = blockIdx.x, t = threadIdx.x;
  const float* hr = h + (size_t)r * DMODEL;
  const u16* ar = ao + (size_t)r * DMODEL;
  float4 xh = *(const float4*)(hr + t * 4);
  ushort4 xa = *(const ushort4*)(ar + t * 4);
  float4 x = {xh.x + bf2f(xa.x), xh.y + bf2f(xa.y),
              xh.z + bf2f(xa.z), xh.w + bf2f(xa.w)};
  float sum = x.x + x.y + x.z + x.w;
  float sq = x.x * x.x + x.y * x.y + x.z * x.z + x.w * x.w;
#pragma unroll
  for (int o = 32; o >= 1; o >>= 1) {
    sum += __shfl_xor(sum, o);
    sq += __shfl_xor(sq, o);
  }
  __shared__ float s_sum[4], s_sq[4];
  int w = t >> 6;
  if ((t & 63) == 0) { s_sum[w] = sum; s_sq[w] = sq; }
  __syncthreads();
  sum = s_sum[0] + s_sum[1] + s_sum[2] + s_sum[3];
  sq = s_sq[0] + s_sq[1] + s_sq[2] + s_sq[3];
  float mean = sum * (1.0f / DMODEL);
  float var = sq * (1.0f / DMODEL) - mean * mean;
  float rstd = rsqrtf(var + EPS_LN);
  float4 g = *(const float4*)(gamma + t * 4);
  float4 bb = *(const float4*)(beta + t * 4);
  float4 o4 = {g.x * (x.x - mean) * rstd + bb.x,
               g.y * (x.y - mean) * rstd + bb.y,
               g.z * (x.z - mean) * rstd + bb.z,
               g.w * (x.w - mean) * rstd + bb.w};
  *(float4*)(out + (size_t)r * DMODEL + t * 4) = o4;
}

extern "C" void kernel_launch(void* const* d_in, const int* in_sizes, int n_in,
                              void* d_out, int out_size, void* d_ws, size_t ws_size,
                              hipStream_t stream) {
  const float* h = (const float*)d_in[0];
  const float* Wq = (const float*)d_in[1];
  const float* Wkv = (const float*)d_in[2];
  const float* Wo = (const float*)d_in[3];
  const float* gamma = (const float*)d_in[4];
  const float* beta = (const float*)d_in[5];
  float* out = (float*)d_out;

  // flat slabs (u16-elem offsets), total ~162 MB, no overlays
  u16* proj = (u16*)d_ws;                        // [3072][3072] bf16
  u16* kft = proj + 9437184;                     // [32]*589824 u16
  u16* kfTt = kft + 18874368;                    // [32]*589824 u16
  u16* vTt = kfTt + 18874368;                    // [32]*98304 u16
  u16* kvswz = vTt + 3145728;                    // [32][24][4][12][512] u16
  float* ksumst = (float*)(kvswz + 18874368);    // [32][24][384] f32
  u16* Wo_bf = (u16*)(ksumst + 294912);          // [1024][1024] u16
  u16* h_bf = Wo_bf + 1048576;                   // [3072][1024] u16
  u16* Wqkv_bf = h_bf + 3145728;                 // [3072][1024] u16
  u16* attnvec = Wqkv_bf + 3145728;              // [3072][1024] u16
  u16* attnout = attnvec + 3145728;              // [3072][1024] u16

  hipLaunchKernelGGL(cvt_all, dim3(7168), dim3(256), 0, stream,
                     h, Wq, Wkv, Wo, h_bf, Wqkv_bf, Wo_bf);
  hipLaunchKernelGGL(gemm_qkv_bf16, dim3(1152), dim3(256), 0, stream,
                     h_bf, Wqkv_bf, proj, ROWS, 3072, 1024);
  hipLaunchKernelGGL(dpfp_k64, dim3(24, 32), dim3(256), 0, stream,
                     proj, kft, kfTt, vTt);
  hipLaunchKernelGGL(chunk_kv_scan, dim3(384), dim3(256), 0, stream,
                     kfTt, vTt, kvswz, ksumst);
  hipLaunchKernelGGL(attn_mfma, dim3(24, 32), dim3(256), 0, stream,
                     proj, kft, vTt, kvswz, ksumst, attnvec);
  hipLaunchKernelGGL(gemm64_bf16, dim3(16, 48), dim3(256), 0, stream,
                     attnvec, Wo_bf, attnout, ROWS, 1024, 1024);
  hipLaunchKernelGGL(ln_kernel, dim3(3072), dim3(256), 0, stream,
                     h, attnout, gamma, beta, out);
}